// Round 5
// baseline (265.244 us; speedup 1.0000x reference)
//
#include <hip/hip_runtime.h>
#include <math.h>

#define EN 16

// mono(x) = exp(-(x*w1 + b1)) . w2 + b2  — fast native exp.
// Gate-safety: angle gates depend only on force *direction*, never on mono
// magnitudes, so __expf's ~1ulp deviation cannot flip a gate.
__device__ __forceinline__ float mono_fast(float x,
    const float* __restrict__ w1, const float* __restrict__ b1,
    const float* __restrict__ w2, const float* __restrict__ b2) {
    float acc = 0.0f;
#pragma unroll
    for (int e = 0; e < EN; ++e) {
        float pre = fmaf(x, w1[e], b1[e]);
        acc = fmaf(__expf(-pre), w2[e], acc);
    }
    return acc + b2[0];
}

// Pre-kernel: del-net mono at x=1.0, identical instruction sequence as the
// main kernel's mono_fast -> bit-identical value (uniform fast path).
extern "C" __global__ void sfm_pre(const float* __restrict__ del_w1,
                                   const float* __restrict__ del_b1,
                                   const float* __restrict__ del_w2,
                                   const float* __restrict__ del_b2,
                                   float* __restrict__ ws) {
    if (threadIdx.x == 0 && blockIdx.x == 0)
        ws[0] = mono_fast(1.0f, del_w1, del_b1, del_w2, del_b2);
}

// Per-agent input state held in registers during the pipelined loop.
struct AgentIn {
    float4 na;  float nvy;   // nei row (id,x,y,vx | vy)
    float2 rc;               // recording slot (id, ct)
    float4 ea, eb, ec, ed;   // ego row cols 0..15
};

__device__ __forceinline__ AgentIn load_agent(
    const float* __restrict__ nei, const float* __restrict__ rec,
    const float* __restrict__ ego, int n, int k) {
    AgentIn s;
    const float* nb = nei + (size_t)n * 128 + (size_t)k * 16;
    s.na  = *(const float4*)nb;
    s.nvy = nb[4];
    s.rc  = *(const float2*)(rec + (size_t)n * 16 + (size_t)k * 2);
    const float* er = ego + (size_t)n * 16;
    s.ea = *(const float4*)(er);
    s.eb = *(const float4*)(er + 4);
    s.ec = *(const float4*)(er + 8);
    s.ed = *(const float4*)(er + 12);
    return s;
}

// Per-agent body — arithmetic bit-identical to the verified round-0/4 kernel
// (same ops, same gates, same xor-butterfly association, same fast path).
__device__ __forceinline__ void compute_agent(
    const AgentIn& s, int n, int k, int gbase, bool valid,
    float ang, float p0, float p1, float b0v, float b3v, float del1,
    const float* __restrict__ rep_w1, const float* __restrict__ rep_b1,
    const float* __restrict__ rep_w2, const float* __restrict__ rep_b2,
    const float* __restrict__ att_w1, const float* __restrict__ att_b1,
    const float* __restrict__ att_w2, const float* __restrict__ att_b2,
    const float* __restrict__ bor_w1, const float* __restrict__ bor_b1,
    const float* __restrict__ bor_w2, const float* __restrict__ bor_b2,
    const float* __restrict__ del_w1, const float* __restrict__ del_b1,
    const float* __restrict__ del_w2, const float* __restrict__ del_b2,
    float* __restrict__ out)
{
    const float nid = s.na.x;
    const float bid = s.rc.x, bct = s.rc.y;

    // uniform fast-path test (wave-wide, no divergence): if every bid==0 and
    // no nid==0, fin is false everywhere -> all counts are the fill value 1.0.
    unsigned long long zb = __ballot(bid != 0.0f);
    unsigned long long zn = __ballot(nid == 0.0f);

    float cntk, delv;
    if (__builtin_expect((zb | zn) == 0ull, 1)) {
        cntk = 1.0f;
        delv = del1;
    } else {
        bool fin = (bid == nid);
#pragma unroll
        for (int t = 1; t < 8; ++t)
            fin = fin || (bid == __shfl_xor(nid, t));
        unsigned long long bal = __ballot(fin);
        unsigned finM = (unsigned)((bal >> gbase) & 0xFFull);
        int popcFin = __popc(finM);
        int jsel = 0, cbits = 0;
#pragma unroll
        for (int j = 0; j < 8; ++j) {
            int bit = (finM >> j) & 1;
            if (bit && cbits == k) jsel = j;
            cbits += bit;
        }
        float bctj = __shfl(bct, gbase + jsel);
        cntk = (k < popcFin) ? (bctj + 1.0f) : 1.0f;
        delv = mono_fast(cntk, del_w1, del_b1, del_w2, del_b2);
    }

    const float px = s.ea.y, py = s.ea.z, vx = s.ea.w, vy = s.eb.x;
    const float speed = sqrtf(vx * vx + vy * vy);

    bool match = (nid == s.eb.w) || (nid == s.ec.x) || (nid == s.ec.y) || (nid == s.ec.z)
              || (nid == s.ec.w) || (nid == s.ed.x) || (nid == s.ed.y) || (nid == s.ed.z);
    const bool idxk = match && (nid != 0.0f);

    float rx = idxk ? (s.na.y - px) : 0.0f;
    float ry = idxk ? (s.na.z - py) : 0.0f;
    float rn = sqrtf(rx * rx + ry * ry);
    float rns = idxk ? rn : 1.0f;
    float dx = rx / rns, dy = ry / rns;

    float att = mono_fast(rn, att_w1, att_b1, att_w2, att_b2);
    float sa = delv * att;
    float fax = idxk ? sa * dx : 0.0f;
    float fay = idxk ? sa * dy : 0.0f;

    float nbx = 0.0f, nby = 0.0f;
    {
        float num = vx * fax + vy * fay;
        float fn = sqrtf(fax * fax + fay * fay);
        float den = fmaxf(speed * fn, 1e-8f);
        if (fabsf(num / den) > ang) { nbx += fax; nby += fay; }
    }

    float sxv = s.na.w * 0.02f, syv = s.nvy * 0.02f;
    float ox = rx + sxv, oy = ry + syv;
    float bsum = rn + (ox * ox + oy * oy) - (sxv * sxv + syv * syv);
    float bgate = idxk ? bsum : 1.0f;
    float bb = sqrtf(fmaxf(bgate, 1e-12f)) * 0.5f;
    float rep = mono_fast(bb, rep_w1, rep_b1, rep_w2, rep_b2);
    float frx = idxk ? rep * dx : 0.0f;
    float fry = idxk ? rep * dy : 0.0f;
    {
        float num = vx * frx + vy * fry;
        float fn = sqrtf(frx * frx + fry * fry);
        float den = fmaxf(speed * fn, 1e-8f);
        if (fabsf(num / den) > ang) { nbx += frx; nby += fry; }
    }

    float bsel = (k == 0) ? b0v : b3v;
    float rb = py - bsel;
    float rbn = fabsf(rb);
    float mb = mono_fast(rbn, bor_w1, bor_b1, bor_w2, bor_b2);
    float fby = mb * (rb / rbn);
    float bory = 0.0f;
    {
        float num = vy * fby;
        float den = fmaxf(speed * fabsf(fby), 1e-8f);
        if ((fabsf(num / den) > ang) && (k < 2)) bory = fby;
    }

#pragma unroll
    for (int m = 1; m < 8; m <<= 1) {
        nbx  += __shfl_xor(nbx,  m);
        nby  += __shfl_xor(nby,  m);
        bory += __shfl_xor(bory, m);
    }

    float fdx = (p1 * speed - vx) / p0;
    float fdy = (0.0f - vy) / p0;
    float fdex = 0.0f, fdey = 0.0f;
    {
        float num = vx * fdx + vy * fdy;
        float fn = sqrtf(fdx * fdx + fdy * fdy);
        float den = fmaxf(speed * fn, 1e-8f);
        if (fabsf(num / den) > ang) { fdex = fdx; fdey = fdy; }
    }

    float wv = (k == 0) ? fdex
             : (k == 1) ? fdey
             : (k == 2) ? nbx
             : (k == 3) ? nby
             : (k == 4) ? 0.0f
             : bory;
    if (valid && k < 6) out[(size_t)n * 6 + k] = wv;
}

// Round-5: software-pipelined multi-agent waves. Each 8-lane group handles
// AG=4 consecutive agents sequentially with a 2-slot register prefetch:
// agent i+1's loads are issued before agent i's ~1.4k-cycle compute body,
// hiding the ~900-cycle HBM first-touch latency via ILP (TLP is VGPR-capped
// at ~4 waves/SIMD and round-3 showed forcing more residency doesn't pay).
extern "C" __global__ void __launch_bounds__(256)
sfm_kernel(const float* __restrict__ ego, const float* __restrict__ nei,
           const float* __restrict__ border, const float* __restrict__ rec,
           const float* __restrict__ p_dest, const float* __restrict__ angle,
           const float* __restrict__ rep_w1, const float* __restrict__ rep_b1,
           const float* __restrict__ rep_w2, const float* __restrict__ rep_b2,
           const float* __restrict__ att_w1, const float* __restrict__ att_b1,
           const float* __restrict__ att_w2, const float* __restrict__ att_b2,
           const float* __restrict__ bor_w1, const float* __restrict__ bor_b1,
           const float* __restrict__ bor_w2, const float* __restrict__ bor_b2,
           const float* __restrict__ del_w1, const float* __restrict__ del_b1,
           const float* __restrict__ del_w2, const float* __restrict__ del_b2,
           const float* __restrict__ del1p,
           float* __restrict__ out, int N)
{
    const int gid = blockIdx.x * blockDim.x + threadIdx.x;
    const int g = gid >> 3;          // agent group: agents 4g .. 4g+3
    const int k = gid & 7;
    const int n0 = g * 4;
    if (n0 >= N) return;
    const int lane = threadIdx.x & 63;
    const int gbase = lane & ~7;

    // uniform scalars (hoisted; same values/ops as the verified kernel)
    const float ang = angle[0];
    const float p0 = p_dest[0], p1 = p_dest[1];
    const float b0v = border[0], b3v = border[3];
    const float del1 = del1p ? del1p[0]
                             : mono_fast(1.0f, del_w1, del_b1, del_w2, del_b2);
    const int nmax = N - 1;

    // 2-slot pipeline over 4 agents: load(i+1) issued before compute(i)
    AgentIn sA = load_agent(nei, rec, ego, min(n0 + 0, nmax), k);
    AgentIn sB = load_agent(nei, rec, ego, min(n0 + 1, nmax), k);

    compute_agent(sA, n0 + 0, k, gbase, (n0 + 0) < N, ang, p0, p1, b0v, b3v, del1,
                  rep_w1, rep_b1, rep_w2, rep_b2, att_w1, att_b1, att_w2, att_b2,
                  bor_w1, bor_b1, bor_w2, bor_b2, del_w1, del_b1, del_w2, del_b2, out);
    sA = load_agent(nei, rec, ego, min(n0 + 2, nmax), k);

    compute_agent(sB, n0 + 1, k, gbase, (n0 + 1) < N, ang, p0, p1, b0v, b3v, del1,
                  rep_w1, rep_b1, rep_w2, rep_b2, att_w1, att_b1, att_w2, att_b2,
                  bor_w1, bor_b1, bor_w2, bor_b2, del_w1, del_b1, del_w2, del_b2, out);
    sB = load_agent(nei, rec, ego, min(n0 + 3, nmax), k);

    compute_agent(sA, n0 + 2, k, gbase, (n0 + 2) < N, ang, p0, p1, b0v, b3v, del1,
                  rep_w1, rep_b1, rep_w2, rep_b2, att_w1, att_b1, att_w2, att_b2,
                  bor_w1, bor_b1, bor_w2, bor_b2, del_w1, del_b1, del_w2, del_b2, out);

    compute_agent(sB, n0 + 3, k, gbase, (n0 + 3) < N, ang, p0, p1, b0v, b3v, del1,
                  rep_w1, rep_b1, rep_w2, rep_b2, att_w1, att_b1, att_w2, att_b2,
                  bor_w1, bor_b1, bor_w2, bor_b2, del_w1, del_b1, del_w2, del_b2, out);
}

extern "C" void kernel_launch(void* const* d_in, const int* in_sizes, int n_in,
                              void* d_out, int out_size, void* d_ws, size_t ws_size,
                              hipStream_t stream) {
    const float* ego    = (const float*)d_in[0];
    const float* nei    = (const float*)d_in[1];
    const float* border = (const float*)d_in[2];
    const float* rec    = (const float*)d_in[3];
    const float* p_dest = (const float*)d_in[4];
    const float* angle  = (const float*)d_in[5];
    const float* rep_w1 = (const float*)d_in[6];
    const float* rep_b1 = (const float*)d_in[7];
    const float* rep_w2 = (const float*)d_in[8];
    const float* rep_b2 = (const float*)d_in[9];
    const float* att_w1 = (const float*)d_in[10];
    const float* att_b1 = (const float*)d_in[11];
    const float* att_w2 = (const float*)d_in[12];
    const float* att_b2 = (const float*)d_in[13];
    const float* bor_w1 = (const float*)d_in[14];
    const float* bor_b1 = (const float*)d_in[15];
    const float* bor_w2 = (const float*)d_in[16];
    const float* bor_b2 = (const float*)d_in[17];
    const float* del_w1 = (const float*)d_in[18];
    const float* del_b1 = (const float*)d_in[19];
    const float* del_w2 = (const float*)d_in[20];
    const float* del_b2 = (const float*)d_in[21];
    float* out = (float*)d_out;

    int N = in_sizes[0] / 16;

    float* del1p = nullptr;
    if (ws_size >= sizeof(float)) {
        del1p = (float*)d_ws;
        sfm_pre<<<1, 64, 0, stream>>>(del_w1, del_b1, del_w2, del_b2, del1p);
    }

    long long groups = (N + 3) / 4;
    long long threads = groups * 8;
    dim3 grid((unsigned)((threads + 255) / 256));
    sfm_kernel<<<grid, 256, 0, stream>>>(
        ego, nei, border, rec, p_dest, angle,
        rep_w1, rep_b1, rep_w2, rep_b2,
        att_w1, att_b1, att_w2, att_b2,
        bor_w1, bor_b1, bor_w2, bor_b2,
        del_w1, del_b1, del_w2, del_b2,
        del1p, out, N);
}

// Round 6
// 257.980 us; speedup vs baseline: 1.0282x; 1.0282x over previous
//
#include <hip/hip_runtime.h>
#include <math.h>

#define EN 16

// mono(x) = exp(-(x*w1 + b1)) . w2 + b2  — fast native exp.
// Gate-safety: angle gates depend only on force *direction*, never on mono
// magnitudes, so __expf's ~1ulp deviation cannot flip a gate.
__device__ __forceinline__ float mono_fast(float x,
    const float* __restrict__ w1, const float* __restrict__ b1,
    const float* __restrict__ w2, const float* __restrict__ b2) {
    float acc = 0.0f;
#pragma unroll
    for (int e = 0; e < EN; ++e) {
        float pre = fmaf(x, w1[e], b1[e]);
        acc = fmaf(__expf(-pre), w2[e], acc);
    }
    return acc + b2[0];
}

// Pre-kernel: del-net mono at x=1.0, identical instruction sequence as the
// main kernel's mono_fast -> bit-identical value (uniform fast path).
extern "C" __global__ void sfm_pre(const float* __restrict__ del_w1,
                                   const float* __restrict__ del_b1,
                                   const float* __restrict__ del_w2,
                                   const float* __restrict__ del_b2,
                                   float* __restrict__ ws) {
    if (threadIdx.x == 0 && blockIdx.x == 0)
        ws[0] = mono_fast(1.0f, del_w1, del_b1, del_w2, del_b2);
}

// Per-(n,k) force contribution — arithmetic bit-identical to the verified
// R2/R5 kernels (same divides, same gate expressions); del mono hoisted to
// the caller (delv), as verified in R5.
__device__ __forceinline__ void do_neighbor(
    float4 na, float nvy, float delv,
    float px, float py, float vx, float vy, float speed, float ang,
    float m0, float m1, float m2, float m3,
    float m4, float m5, float m6, float m7,
    const float* __restrict__ rep_w1, const float* __restrict__ rep_b1,
    const float* __restrict__ rep_w2, const float* __restrict__ rep_b2,
    const float* __restrict__ att_w1, const float* __restrict__ att_b1,
    const float* __restrict__ att_w2, const float* __restrict__ att_b2,
    float& cxk, float& cyk)
{
    const float nid = na.x;
    bool match = (nid == m0) || (nid == m1) || (nid == m2) || (nid == m3)
              || (nid == m4) || (nid == m5) || (nid == m6) || (nid == m7);
    const bool idxk = match && (nid != 0.0f);

    float rx = idxk ? (na.y - px) : 0.0f;
    float ry = idxk ? (na.z - py) : 0.0f;
    float rn = sqrtf(rx * rx + ry * ry);
    float rns = idxk ? rn : 1.0f;
    float dx = rx / rns, dy = ry / rns;

    // attraction = mono_del(count) * mono_att(rn) * dir
    float att = mono_fast(rn, att_w1, att_b1, att_w2, att_b2);
    float sa = delv * att;
    float fax = idxk ? sa * dx : 0.0f;
    float fay = idxk ? sa * dy : 0.0f;

    cxk = 0.0f; cyk = 0.0f;
    {
        float num = vx * fax + vy * fay;
        float fn = sqrtf(fax * fax + fay * fay);
        float den = fmaxf(speed * fn, 1e-8f);
        if (fabsf(num / den) > ang) { cxk += fax; cyk += fay; }
    }

    // repulsion
    float sxv = na.w * 0.02f, syv = nvy * 0.02f;
    float ox = rx + sxv, oy = ry + syv;
    float bsum = rn + (ox * ox + oy * oy) - (sxv * sxv + syv * syv);
    float bgate = idxk ? bsum : 1.0f;
    float bb = sqrtf(fmaxf(bgate, 1e-12f)) * 0.5f;
    float rep = mono_fast(bb, rep_w1, rep_b1, rep_w2, rep_b2);
    float frx = idxk ? rep * dx : 0.0f;
    float fry = idxk ? rep * dy : 0.0f;
    {
        float num = vx * frx + vy * fry;
        float fn = sqrtf(frx * frx + fry * fry);
        float den = fmaxf(speed * fn, 1e-8f);
        if (fabsf(num / den) > ang) { cxk += frx; cyk += fry; }
    }
}

// Round-6: R2's 4-lane/agent structure (lowest per-agent wave-instruction
// cost, verified) + R4's uniform recording-buffer fast path (verified).
// Rationale: R5's counters show the workload is ~59% VALU-issue-bound at
// the 67us cluster; only exact instruction removal can win. Fast path cuts
// 2 del monos, the fin shuffle chain and 2 select chains per stream-unit.
// Slow path retains R2's verified logic for arbitrary inputs.
extern "C" __global__ void __launch_bounds__(256)
sfm_kernel(const float* __restrict__ ego, const float* __restrict__ nei,
           const float* __restrict__ border, const float* __restrict__ rec,
           const float* __restrict__ p_dest, const float* __restrict__ angle,
           const float* __restrict__ rep_w1, const float* __restrict__ rep_b1,
           const float* __restrict__ rep_w2, const float* __restrict__ rep_b2,
           const float* __restrict__ att_w1, const float* __restrict__ att_b1,
           const float* __restrict__ att_w2, const float* __restrict__ att_b2,
           const float* __restrict__ bor_w1, const float* __restrict__ bor_b1,
           const float* __restrict__ bor_w2, const float* __restrict__ bor_b2,
           const float* __restrict__ del_w1, const float* __restrict__ del_b1,
           const float* __restrict__ del_w2, const float* __restrict__ del_b2,
           const float* __restrict__ del1p,
           float* __restrict__ out, int N)
{
    const int gid = blockIdx.x * blockDim.x + threadIdx.x;
    const int n = gid >> 2;      // agent
    const int s = gid & 3;       // sub-lane: neighbors 2s, 2s+1
    if (n >= N) return;
    const int lane = threadIdx.x & 63;
    const int gbase = lane & ~3; // first lane of this agent's 4-lane group

    const float ang = angle[0];
    const float p0 = p_dest[0], p1 = p_dest[1];

    // my two neighbor rows (cols 0..4); 32-bit offsets (buffers < 4GB)
    const int k0 = 2 * s, k1 = 2 * s + 1;
    const float* nb = nei + ((unsigned)n * 128u);
    float4 na0 = *(const float4*)(nb + k0 * 16);
    float  nv0 = nb[k0 * 16 + 4];
    float4 na1 = *(const float4*)(nb + k1 * 16);
    float  nv1 = nb[k1 * 16 + 4];

    // my two recording slots (2s, 2s+1): coalesced 16B/lane
    float4 rcv = *(const float4*)(rec + ((unsigned)n * 16u + (unsigned)s * 4u));
    const float bidA = rcv.x, bctA = rcv.y;
    const float bidB = rcv.z, bctB = rcv.w;

    const float g0 = na0.x, g1 = na1.x;

    // ---- uniform fast-path test (wave-wide, no divergence) ----
    // If every buffer id is 0 and no neighbor id is 0, fin is false for all
    // slots -> every count takes the fill value 1.0 (verified in R4).
    unsigned long long zb = __ballot((bidA != 0.0f) || (bidB != 0.0f));
    unsigned long long zn = __ballot((g0 == 0.0f) || (g1 == 0.0f));

    float delv0, delv1;
    if (__builtin_expect((zb | zn) == 0ull, 1)) {
        const float del1 = del1p ? del1p[0]
                                 : mono_fast(1.0f, del_w1, del_b1, del_w2, del_b2);
        delv0 = del1;
        delv1 = del1;
    } else {
        // ---- full (verified R2) path ----
        const float x1a = __shfl_xor(g0, 1), x1b = __shfl_xor(g1, 1);
        const float x2a = __shfl_xor(g0, 2), x2b = __shfl_xor(g1, 2);
        const float x3a = __shfl_xor(g0, 3), x3b = __shfl_xor(g1, 3);

        bool finA = (bidA == g0) || (bidA == g1) || (bidA == x1a) || (bidA == x1b)
                 || (bidA == x2a) || (bidA == x2b) || (bidA == x3a) || (bidA == x3b);
        bool finB = (bidB == g0) || (bidB == g1) || (bidB == x1a) || (bidB == x1b)
                 || (bidB == x2a) || (bidB == x2b) || (bidB == x3a) || (bidB == x3b);

        unsigned long long balA = __ballot(finA);
        unsigned long long balB = __ballot(finB);
        unsigned mA = (unsigned)((balA >> gbase) & 0xFull); // bit l = fin[2l]
        unsigned mB = (unsigned)((balB >> gbase) & 0xFull); // bit l = fin[2l+1]
        unsigned finM = 0;
#pragma unroll
        for (int l = 0; l < 4; ++l)
            finM |= (((mA >> l) & 1u) << (2 * l)) | (((mB >> l) & 1u) << (2 * l + 1));
        const int popcFin = __popc(finM);

        float cntv[2];
#pragma unroll
        for (int t = 0; t < 2; ++t) {
            const int k = 2 * s + t;
            int jsel = 0, cbits = 0;
#pragma unroll
            for (int j = 0; j < 8; ++j) {
                int bit = (finM >> j) & 1;
                if (bit && cbits == k) jsel = j;
                cbits += bit;
            }
            int owner = gbase + (jsel >> 1);         // lane holding slot jsel
            float lo = __shfl(bctA, owner);          // bct[2*(jsel>>1)]
            float hi = __shfl(bctB, owner);          // bct[2*(jsel>>1)+1]
            float bj = (jsel & 1) ? hi : lo;         // bct[jsel]
            cntv[t] = (k < popcFin) ? (bj + 1.0f) : 1.0f;
        }
        delv0 = mono_fast(cntv[0], del_w1, del_b1, del_w2, del_b2);
        delv1 = mono_fast(cntv[1], del_w1, del_b1, del_w2, del_b2);
    }

    // ego row (same 64B line for all 4 lanes -> L1 broadcast)
    const float* er = ego + ((unsigned)n * 16u);
    float4 ea = *(const float4*)(er);       // cols 0..3
    float4 eb = *(const float4*)(er + 4);   // cols 4..7
    float4 ec = *(const float4*)(er + 8);   // cols 8..11
    float4 ed = *(const float4*)(er + 12);  // cols 12..15
    const float px = ea.y, py = ea.z, vx = ea.w, vy = eb.x;
    const float speed = sqrtf(vx * vx + vy * vy);
    const float m0 = eb.w, m1 = ec.x, m2 = ec.y, m3 = ec.z;
    const float m4 = ec.w, m5 = ed.x, m6 = ed.y, m7 = ed.z;

    // my two neighbors; pair sum p_s = cx(2s) + cx(2s+1)
    float cx0, cy0, cx1, cy1;
    do_neighbor(na0, nv0, delv0, px, py, vx, vy, speed, ang,
                m0, m1, m2, m3, m4, m5, m6, m7,
                rep_w1, rep_b1, rep_w2, rep_b2,
                att_w1, att_b1, att_w2, att_b2, cx0, cy0);
    do_neighbor(na1, nv1, delv1, px, py, vx, vy, speed, ang,
                m0, m1, m2, m3, m4, m5, m6, m7,
                rep_w1, rep_b1, rep_w2, rep_b2,
                att_w1, att_b1, att_w2, att_b2, cx1, cy1);
    float pxs = cx0 + cx1;
    float pys = cy0 + cy1;

    // border force (y-only): slot s=0 -> border[0], s=1 -> border[3];
    // s=2,3 compute a dummy (uniform instruction stream) gated to zero.
    float gb = 0.0f;
    {
        float bsel = (s == 1) ? border[3] : border[0];
        float rb = py - bsel;
        float rbn = fabsf(rb);
        float mb = mono_fast(rbn, bor_w1, bor_b1, bor_w2, bor_b2);
        float fby = mb * (rb / rbn);
        float num = vy * fby;
        float den = fmaxf(speed * fabsf(fby), 1e-8f);
        if ((fabsf(num / den) > ang) && (s < 2)) gb = fby;
    }

    // xor-butterfly over the 4-lane group: ((p0+p1)+(p2+p3)) — identical
    // association to the verified kernels; border gets (g0+g1)+(0+0)=g0+g1.
    pxs += __shfl_xor(pxs, 1);  pys += __shfl_xor(pys, 1);  gb += __shfl_xor(gb, 1);
    pxs += __shfl_xor(pxs, 2);  pys += __shfl_xor(pys, 2);  gb += __shfl_xor(gb, 2);

    // destination force (uniform, cheap: compute everywhere)
    float fdx = (p1 * speed - vx) / p0;
    float fdy = (0.0f - vy) / p0;
    float fdex = 0.0f, fdey = 0.0f;
    {
        float num = vx * fdx + vy * fdy;
        float fn = sqrtf(fdx * fdx + fdy * fdy);
        float den = fmaxf(speed * fn, 1e-8f);
        if (fabsf(num / den) > ang) { fdex = fdx; fdey = fdy; }
    }

    // output (N,3,2): lanes s=0,1,2 each store one float2 (24B/agent contiguous)
    float2 wv = (s == 0) ? make_float2(fdex, fdey)
              : (s == 1) ? make_float2(pxs, pys)
              :            make_float2(0.0f, gb);
    if (s < 3) *(float2*)(out + ((unsigned)n * 6u + 2u * (unsigned)s)) = wv;
}

extern "C" void kernel_launch(void* const* d_in, const int* in_sizes, int n_in,
                              void* d_out, int out_size, void* d_ws, size_t ws_size,
                              hipStream_t stream) {
    const float* ego    = (const float*)d_in[0];
    const float* nei    = (const float*)d_in[1];
    const float* border = (const float*)d_in[2];
    const float* rec    = (const float*)d_in[3];
    const float* p_dest = (const float*)d_in[4];
    const float* angle  = (const float*)d_in[5];
    const float* rep_w1 = (const float*)d_in[6];
    const float* rep_b1 = (const float*)d_in[7];
    const float* rep_w2 = (const float*)d_in[8];
    const float* rep_b2 = (const float*)d_in[9];
    const float* att_w1 = (const float*)d_in[10];
    const float* att_b1 = (const float*)d_in[11];
    const float* att_w2 = (const float*)d_in[12];
    const float* att_b2 = (const float*)d_in[13];
    const float* bor_w1 = (const float*)d_in[14];
    const float* bor_b1 = (const float*)d_in[15];
    const float* bor_w2 = (const float*)d_in[16];
    const float* bor_b2 = (const float*)d_in[17];
    const float* del_w1 = (const float*)d_in[18];
    const float* del_b1 = (const float*)d_in[19];
    const float* del_w2 = (const float*)d_in[20];
    const float* del_b2 = (const float*)d_in[21];
    float* out = (float*)d_out;

    int N = in_sizes[0] / 16;

    float* del1p = nullptr;
    if (ws_size >= sizeof(float)) {
        del1p = (float*)d_ws;
        sfm_pre<<<1, 64, 0, stream>>>(del_w1, del_b1, del_w2, del_b2, del1p);
    }

    long long threads = (long long)N * 4;
    dim3 grid((unsigned)((threads + 255) / 256));
    sfm_kernel<<<grid, 256, 0, stream>>>(
        ego, nei, border, rec, p_dest, angle,
        rep_w1, rep_b1, rep_w2, rep_b2,
        att_w1, att_b1, att_w2, att_b2,
        bor_w1, bor_b1, bor_w2, bor_b2,
        del_w1, del_b1, del_w2, del_b2,
        del1p, out, N);
}